// Round 1
// baseline (21312.007 us; speedup 1.0000x reference)
//
#include <hip/hip_runtime.h>
#include <hip/hip_cooperative_groups.h>

namespace cg = cooperative_groups;

#define B_   64
#define T_   512
#define IN_  512
#define HID_ 1024
#define OUT_ 512

// ---------------------------------------------------------------------------
// K0: transpose W_hh [j][k] (HIDxHID) -> Wt [k][j] so scan-kernel W reads are
// coalesced across lanes (lanes index j).
// ---------------------------------------------------------------------------
__global__ __launch_bounds__(256) void transpose_whh(const float* __restrict__ W,
                                                     float* __restrict__ Wt) {
  __shared__ float tile[32][33];
  const int bx = blockIdx.x * 32;  // k-tile origin
  const int by = blockIdx.y * 32;  // j-tile origin
  const int tx = threadIdx.x;      // 0..31
  const int ty = threadIdx.y;      // 0..7
#pragma unroll
  for (int i = 0; i < 32; i += 8)
    tile[ty + i][tx] = W[(size_t)(by + ty + i) * HID_ + bx + tx];
  __syncthreads();
#pragma unroll
  for (int i = 0; i < 32; i += 8)
    Wt[(size_t)(bx + ty + i) * HID_ + by + tx] = tile[tx][ty + i];
}

// ---------------------------------------------------------------------------
// K1/K3: C[M,N] = A[M,K] @ B[N,K]^T + bias[N].  fp32, 128x128 tile, BK=8,
// 256 threads, 8x8 microtile. All dims divide evenly for our shapes.
// ---------------------------------------------------------------------------
__global__ __launch_bounds__(256) void gemm_bias(const float* __restrict__ A,
                                                 const float* __restrict__ Bm,
                                                 const float* __restrict__ bias,
                                                 float* __restrict__ C,
                                                 int M, int N, int K) {
  __shared__ float As[8][128];
  __shared__ float Bs[8][128];
  const int bm = blockIdx.y * 128;
  const int bn = blockIdx.x * 128;
  const int tid = threadIdx.x;
  const int tr = (tid / 16) * 8;   // 0..120 (row of 8x8 microtile)
  const int tc = (tid % 16) * 8;   // 0..120 (col of 8x8 microtile)
  const int lr = tid / 2;          // 0..127 (staging row)
  const int lk = (tid % 2) * 4;    // 0 or 4 (staging k-offset)

  float acc[8][8];
#pragma unroll
  for (int i = 0; i < 8; i++)
#pragma unroll
    for (int j = 0; j < 8; j++) acc[i][j] = 0.f;

  for (int k0 = 0; k0 < K; k0 += 8) {
    float4 a = *(const float4*)&A[(size_t)(bm + lr) * K + k0 + lk];
    float4 b = *(const float4*)&Bm[(size_t)(bn + lr) * K + k0 + lk];
    As[lk + 0][lr] = a.x; As[lk + 1][lr] = a.y;
    As[lk + 2][lr] = a.z; As[lk + 3][lr] = a.w;
    Bs[lk + 0][lr] = b.x; Bs[lk + 1][lr] = b.y;
    Bs[lk + 2][lr] = b.z; Bs[lk + 3][lr] = b.w;
    __syncthreads();
#pragma unroll
    for (int k = 0; k < 8; k++) {
      float av[8], bv[8];
#pragma unroll
      for (int i = 0; i < 8; i++) av[i] = As[k][tr + i];
#pragma unroll
      for (int j = 0; j < 8; j++) bv[j] = Bs[k][tc + j];
#pragma unroll
      for (int i = 0; i < 8; i++)
#pragma unroll
        for (int j = 0; j < 8; j++) acc[i][j] += av[i] * bv[j];
    }
    __syncthreads();
  }

#pragma unroll
  for (int i = 0; i < 8; i++) {
#pragma unroll
    for (int j = 0; j < 8; j += 4) {
      float4 o;
      o.x = acc[i][j + 0] + bias[bn + tc + j + 0];
      o.y = acc[i][j + 1] + bias[bn + tc + j + 1];
      o.z = acc[i][j + 2] + bias[bn + tc + j + 2];
      o.w = acc[i][j + 3] + bias[bn + tc + j + 3];
      *(float4*)&C[(size_t)(bm + tr + i) * N + bn + tc + j] = o;
    }
  }
}

// ---------------------------------------------------------------------------
// K2: persistent cooperative scan kernel.
// hall starts as x_proj [B*T][HID] (row = b*T + t) and is overwritten in
// place with h_t.  Partition: 32 j-slices (32 cols each) x 8 b-groups (8 b
// each) = 256 blocks.  jg = bid%32 spreads j-slices across XCDs so each
// XCD's L2 only needs ~512 KB of Wt per step.
// Thread map (256 thr): q = tid%8 -> j-quad, bl = (tid/8)%8 -> batch,
// ks = tid/64 -> one of 4 K-splits (each wave owns one contiguous K range).
// ---------------------------------------------------------------------------
__global__ __launch_bounds__(256) void rnn_scan(const float* __restrict__ Wt,
                                                float* __restrict__ hall) {
  cg::grid_group grid = cg::this_grid();
  __shared__ float red[4][64][4];  // [ks][oq][4 j]

  const int bid = blockIdx.x;
  const int jg = bid % 32;
  const int bg = bid / 32;
  const int j0 = jg * 32;
  const int b0 = bg * 8;
  const int tid = threadIdx.x;
  const int q  = tid % 8;
  const int bl = (tid / 8) % 8;
  const int ks = tid / 64;
  const int j  = j0 + q * 4;
  const int b  = b0 + bl;
  const int k0 = ks * 256;
  const int oq = bl * 8 + q;

  for (int t = 0; t < T_; t++) {
    float acc0 = 0.f, acc1 = 0.f, acc2 = 0.f, acc3 = 0.f;
    if (t > 0) {
      const float* __restrict__ hrow = &hall[((size_t)b * T_ + (t - 1)) * HID_];
      const float* __restrict__ wp0 = &Wt[(size_t)k0 * HID_ + j];
#pragma unroll 4
      for (int kk = 0; kk < 256; kk += 4) {
        float4 hv = *(const float4*)&hrow[k0 + kk];
        const float* wp = wp0 + (size_t)kk * HID_;
        float4 w0 = *(const float4*)(wp);
        float4 w1 = *(const float4*)(wp + HID_);
        float4 w2 = *(const float4*)(wp + 2 * HID_);
        float4 w3 = *(const float4*)(wp + 3 * HID_);
        acc0 += hv.x * w0.x; acc1 += hv.x * w0.y; acc2 += hv.x * w0.z; acc3 += hv.x * w0.w;
        acc0 += hv.y * w1.x; acc1 += hv.y * w1.y; acc2 += hv.y * w1.z; acc3 += hv.y * w1.w;
        acc0 += hv.z * w2.x; acc1 += hv.z * w2.y; acc2 += hv.z * w2.z; acc3 += hv.z * w2.w;
        acc0 += hv.w * w3.x; acc1 += hv.w * w3.y; acc2 += hv.w * w3.z; acc3 += hv.w * w3.w;
      }
    }
    red[ks][oq][0] = acc0;
    red[ks][oq][1] = acc1;
    red[ks][oq][2] = acc2;
    red[ks][oq][3] = acc3;
    __syncthreads();
    if (tid < 64) {
      const int b_r = b0 + tid / 8;
      const int j_r = j0 + (tid % 8) * 4;
      float4 s;
      s.x = red[0][tid][0] + red[1][tid][0] + red[2][tid][0] + red[3][tid][0];
      s.y = red[0][tid][1] + red[1][tid][1] + red[2][tid][1] + red[3][tid][1];
      s.z = red[0][tid][2] + red[1][tid][2] + red[2][tid][2] + red[3][tid][2];
      s.w = red[0][tid][3] + red[1][tid][3] + red[2][tid][3] + red[3][tid][3];
      float* xprow = &hall[((size_t)b_r * T_ + t) * HID_ + j_r];
      float4 xp = *(const float4*)xprow;
      float4 o;
      o.x = tanhf(s.x + xp.x);
      o.y = tanhf(s.y + xp.y);
      o.z = tanhf(s.z + xp.z);
      o.w = tanhf(s.w + xp.w);
      *(float4*)xprow = o;
    }
    grid.sync();
  }
}

// ---------------------------------------------------------------------------
extern "C" void kernel_launch(void* const* d_in, const int* in_sizes, int n_in,
                              void* d_out, int out_size, void* d_ws, size_t ws_size,
                              hipStream_t stream) {
  (void)in_sizes; (void)n_in; (void)out_size; (void)ws_size;
  const float* input = (const float*)d_in[0];  // [B,T,IN]
  const float* W_ih  = (const float*)d_in[1];  // [HID,IN]
  const float* W_hh  = (const float*)d_in[2];  // [HID,HID]
  const float* bias  = (const float*)d_in[3];  // [HID]
  const float* W_out = (const float*)d_in[4];  // [OUT,HID]
  const float* b_out = (const float*)d_in[5];  // [OUT]
  float* out = (float*)d_out;                  // [B,T,OUT]

  float* Wt   = (float*)d_ws;                      // 4 MB  (W_hh transposed [k][j])
  float* hall = Wt + (size_t)HID_ * HID_;          // 134 MB (x_proj, then h_all)

  // K0: transpose W_hh
  transpose_whh<<<dim3(32, 32), dim3(32, 8), 0, stream>>>(W_hh, Wt);

  // K1: x_proj = input @ W_ih^T + b   (M=B*T, N=HID, K=IN)
  gemm_bias<<<dim3(HID_ / 128, (B_ * T_) / 128), 256, 0, stream>>>(
      input, W_ih, bias, hall, B_ * T_, HID_, IN_);

  // K2: sequential scan (cooperative, persistent)
  float* WtArg = Wt;
  float* hallArg = hall;
  void* args[] = {(void*)&WtArg, (void*)&hallArg};
  hipLaunchCooperativeKernel((void*)rnn_scan, dim3(256), dim3(256), args, 0, stream);

  // K3: out = h_all @ W_out^T + b_out  (M=B*T, N=OUT, K=HID)
  gemm_bias<<<dim3(OUT_ / 128, (B_ * T_) / 128), 256, 0, stream>>>(
      hall, W_out, b_out, out, B_ * T_, OUT_, HID_);
}

// Round 4
// 9724.322 us; speedup vs baseline: 2.1916x; 2.1916x over previous
//
#include <hip/hip_runtime.h>

#define B_   64
#define T_   512
#define IN_  512
#define HID_ 1024
#define OUT_ 512

#define BROW 1092        // hs staging row stride (floats): 1024 data + skew pads
#define RED_STRIDE 260   // reduction slice stride (floats)
#define HS_FLOATS 8728   // 34.9 KB static LDS

// ---------------------------------------------------------------------------
// K0: transpose W_hh [j][k] -> Wt [k][j] so scan W reads are lane-coalesced.
// ---------------------------------------------------------------------------
__global__ __launch_bounds__(256) void transpose_whh(const float* __restrict__ W,
                                                     float* __restrict__ Wt) {
  __shared__ float tile[32][33];
  const int bx = blockIdx.x * 32;  // k
  const int by = blockIdx.y * 32;  // j
  const int tx = threadIdx.x;
  const int ty = threadIdx.y;
#pragma unroll
  for (int i = 0; i < 32; i += 8)
    tile[ty + i][tx] = W[(size_t)(by + ty + i) * HID_ + bx + tx];
  __syncthreads();
#pragma unroll
  for (int i = 0; i < 32; i += 8)
    Wt[(size_t)(bx + ty + i) * HID_ + by + tx] = tile[tx][ty + i];
}

// ---------------------------------------------------------------------------
// K1/K3: C[M,N] = A[M,K] @ B[N,K]^T + bias[N].  fp32, 128x128 tile, BK=8.
// (unchanged from the passing R1 kernel)
// ---------------------------------------------------------------------------
__global__ __launch_bounds__(256) void gemm_bias(const float* __restrict__ A,
                                                 const float* __restrict__ Bm,
                                                 const float* __restrict__ bias,
                                                 float* __restrict__ C,
                                                 int M, int N, int K) {
  __shared__ float As[8][128];
  __shared__ float Bs[8][128];
  const int bm = blockIdx.y * 128;
  const int bn = blockIdx.x * 128;
  const int tid = threadIdx.x;
  const int tr = (tid / 16) * 8;
  const int tc = (tid % 16) * 8;
  const int lr = tid / 2;
  const int lk = (tid % 2) * 4;

  float acc[8][8];
#pragma unroll
  for (int i = 0; i < 8; i++)
#pragma unroll
    for (int j = 0; j < 8; j++) acc[i][j] = 0.f;

  for (int k0 = 0; k0 < K; k0 += 8) {
    float4 a = *(const float4*)&A[(size_t)(bm + lr) * K + k0 + lk];
    float4 b = *(const float4*)&Bm[(size_t)(bn + lr) * K + k0 + lk];
    As[lk + 0][lr] = a.x; As[lk + 1][lr] = a.y;
    As[lk + 2][lr] = a.z; As[lk + 3][lr] = a.w;
    Bs[lk + 0][lr] = b.x; Bs[lk + 1][lr] = b.y;
    Bs[lk + 2][lr] = b.z; Bs[lk + 3][lr] = b.w;
    __syncthreads();
#pragma unroll
    for (int k = 0; k < 8; k++) {
      float av[8], bv[8];
#pragma unroll
      for (int i = 0; i < 8; i++) av[i] = As[k][tr + i];
#pragma unroll
      for (int j = 0; j < 8; j++) bv[j] = Bs[k][tc + j];
#pragma unroll
      for (int i = 0; i < 8; i++)
#pragma unroll
        for (int j = 0; j < 8; j++) acc[i][j] += av[i] * bv[j];
    }
    __syncthreads();
  }

#pragma unroll
  for (int i = 0; i < 8; i++) {
#pragma unroll
    for (int j = 0; j < 8; j += 4) {
      float4 o;
      o.x = acc[i][j + 0] + bias[bn + tc + j + 0];
      o.y = acc[i][j + 1] + bias[bn + tc + j + 1];
      o.z = acc[i][j + 2] + bias[bn + tc + j + 2];
      o.w = acc[i][j + 3] + bias[bn + tc + j + 3];
      *(float4*)&C[(size_t)(bm + tr + i) * N + bn + tc + j] = o;
    }
  }
}

// ---------------------------------------------------------------------------
// K2: persistent scan, PLAIN launch (256 blocks <= 256 CUs, 35 KB LDS -> all
// co-resident).  256 blocks = 32 j-slices x 8 batch-groups; only the 32
// blocks of a batch-group synchronize (counter barrier, fresh counter per
// (group, t), release-fence + add / spin / acquire-fence).
// h(t-1) is staged into LDS via relaxed AGENT-scope u64 atomic loads (bypass
// stale L1/L2 -> L3 coherence point); h(t) published via AGENT-scope atomic
// stores.  W streamed from L2 (per-XCD footprint ~512 KB, L2-resident).
// Thread map: q=tid&3 -> 8-j octet, bq=(tid>>2)&1 -> 4-batch half,
// ks=tid>>3 (0..31) -> 32-k slice.  Per thread: 8j x 4b x 32k = 1024 FMA.
// ---------------------------------------------------------------------------
__global__ __launch_bounds__(256) void rnn_scan4(const float* __restrict__ Wt,
                                                 float* __restrict__ hall,
                                                 int* __restrict__ cnt) {
  __shared__ float hs[HS_FLOATS];  // staging [8][BROW]; red alias [32][RED_STRIDE]

  const int bid = blockIdx.x;
  const int jg = bid & 31;
  const int bg = bid >> 5;
  const int j0 = jg * 32;
  const int b0 = bg * 8;
  const int tid = threadIdx.x;
  const int q  = tid & 3;
  const int bq = (tid >> 2) & 1;
  const int ks = tid >> 3;

  const float* wbase = Wt + (size_t)(ks * 32) * HID_ + j0 + q * 8;
  const float* hsbase = hs + (bq * 4) * BROW + ks * 32 + (ks >> 1) * 4;

  for (int t = 0; t < T_; ++t) {
    // --- prefetch xp (own j-slice of row t; written only by this block, later)
    float4 xpv = make_float4(0.f, 0.f, 0.f, 0.f);
    float* xpaddr = nullptr;
    if (tid < 64) {
      xpaddr = &hall[((size_t)(b0 + (tid >> 3)) * T_ + t) * HID_ + j0 + (tid & 7) * 4];
      xpv = *(const float4*)xpaddr;
    }

    float4 acc[4][2];
#pragma unroll
    for (int bi = 0; bi < 4; ++bi) {
      acc[bi][0] = make_float4(0.f, 0.f, 0.f, 0.f);
      acc[bi][1] = make_float4(0.f, 0.f, 0.f, 0.f);
    }

    if (t > 0) {
      const int tp = t - 1;
      // --- stage h(t-1): 8 rows x 1024 floats via coherent u64 loads.
      // F2 = float2 index in [8][512]; skew (k2>>5)*4 matches compute reads.
#pragma unroll
      for (int s = 0; s < 16; ++s) {
        const int F2 = tid + 256 * s;
        const int b  = F2 >> 9;
        const int k2 = F2 & 511;
        const unsigned long long* src = (const unsigned long long*)
            &hall[((size_t)(b0 + b) * T_ + tp) * HID_ + 2 * k2];
        unsigned long long v =
            __hip_atomic_load(src, __ATOMIC_RELAXED, __HIP_MEMORY_SCOPE_AGENT);
        *(unsigned long long*)&hs[b * BROW + 2 * k2 + (k2 >> 5) * 4] = v;
      }
      __syncthreads();

      // --- compute: 8 groups of 4 k  (per thread: 4k x 8j x 4b per group)
#pragma unroll
      for (int g = 0; g < 8; ++g) {
        const int kk = g * 4;
        const float* wp = wbase + (size_t)kk * HID_;
        float4 w[4][2];
#pragma unroll
        for (int i = 0; i < 4; ++i) {
          w[i][0] = *(const float4*)(wp + (size_t)i * HID_);
          w[i][1] = *(const float4*)(wp + (size_t)i * HID_ + 4);
        }
#pragma unroll
        for (int bi = 0; bi < 4; ++bi) {
          const float4 hv = *(const float4*)(hsbase + bi * BROW + kk);
#pragma unroll
          for (int jh = 0; jh < 2; ++jh) {
            acc[bi][jh].x += hv.x * w[0][jh].x + hv.y * w[1][jh].x +
                             hv.z * w[2][jh].x + hv.w * w[3][jh].x;
            acc[bi][jh].y += hv.x * w[0][jh].y + hv.y * w[1][jh].y +
                             hv.z * w[2][jh].y + hv.w * w[3][jh].y;
            acc[bi][jh].z += hv.x * w[0][jh].z + hv.y * w[1][jh].z +
                             hv.z * w[2][jh].z + hv.w * w[3][jh].z;
            acc[bi][jh].w += hv.x * w[0][jh].w + hv.y * w[1][jh].w +
                             hv.z * w[2][jh].w + hv.w * w[3][jh].w;
          }
        }
      }
      __syncthreads();  // all hs reads done before red overwrites
    }

    // --- write partial sums to red (aliases hs)
#pragma unroll
    for (int bi = 0; bi < 4; ++bi) {
      float* rp = &hs[ks * RED_STRIDE + (bq * 4 + bi) * 32 + q * 8];
      *(float4*)rp = acc[bi][0];
      *(float4*)(rp + 4) = acc[bi][1];
    }
    __syncthreads();

    // --- reduce 32 k-slices, tanh, publish h(t) to the coherence point
    if (tid < 64) {
      const int off = (tid >> 3) * 32 + (tid & 7) * 4;
      float4 sum = make_float4(0.f, 0.f, 0.f, 0.f);
#pragma unroll
      for (int kss = 0; kss < 32; ++kss) {
        const float4 r = *(const float4*)&hs[kss * RED_STRIDE + off];
        sum.x += r.x; sum.y += r.y; sum.z += r.z; sum.w += r.w;
      }
      union { float f[4]; unsigned long long u[2]; } pk;
      pk.f[0] = tanhf(sum.x + xpv.x);
      pk.f[1] = tanhf(sum.y + xpv.y);
      pk.f[2] = tanhf(sum.z + xpv.z);
      pk.f[3] = tanhf(sum.w + xpv.w);
      unsigned long long* dst = (unsigned long long*)xpaddr;
      __hip_atomic_store(dst + 0, pk.u[0], __ATOMIC_RELAXED, __HIP_MEMORY_SCOPE_AGENT);
      __hip_atomic_store(dst + 1, pk.u[1], __ATOMIC_RELAXED, __HIP_MEMORY_SCOPE_AGENT);
    }
    __syncthreads();  // drains h stores (vmcnt) on every wave before arrival

    // --- per-group 32-block barrier, fresh counter per (bg, t)
    if (tid == 0) {
      int* c = &cnt[bg * T_ + t];
      __builtin_amdgcn_fence(__ATOMIC_RELEASE, "agent");  // L2 writeback
      __hip_atomic_fetch_add(c, 1, __ATOMIC_RELAXED, __HIP_MEMORY_SCOPE_AGENT);
      while (__hip_atomic_load(c, __ATOMIC_RELAXED, __HIP_MEMORY_SCOPE_AGENT) < 32) {
      }
      __builtin_amdgcn_fence(__ATOMIC_ACQUIRE, "agent");  // L1/L2 invalidate
    }
    __syncthreads();
  }
}

// ---------------------------------------------------------------------------
extern "C" void kernel_launch(void* const* d_in, const int* in_sizes, int n_in,
                              void* d_out, int out_size, void* d_ws, size_t ws_size,
                              hipStream_t stream) {
  (void)in_sizes; (void)n_in; (void)out_size; (void)ws_size;
  const float* input = (const float*)d_in[0];
  const float* W_ih  = (const float*)d_in[1];
  const float* W_hh  = (const float*)d_in[2];
  const float* bias  = (const float*)d_in[3];
  const float* W_out = (const float*)d_in[4];
  const float* b_out = (const float*)d_in[5];
  float* out = (float*)d_out;

  // Workspace layout identical to the passing R1 kernel (no growth):
  float* Wt   = (float*)d_ws;                  // 4 MiB
  float* hall = Wt + (size_t)HID_ * HID_;      // 128 MiB (x_proj, then h)
  // Barrier counters live in the head of d_out: zeroed here, used by the
  // scan, then fully overwritten by K3's output writes.
  int* cnt = (int*)d_out;                      // 8 groups x 512 steps x 4 B = 16 KiB

  hipMemsetAsync(cnt, 0, 8 * T_ * sizeof(int), stream);

  transpose_whh<<<dim3(32, 32), dim3(32, 8), 0, stream>>>(W_hh, Wt);

  gemm_bias<<<dim3(HID_ / 128, (B_ * T_) / 128), 256, 0, stream>>>(
      input, W_ih, bias, hall, B_ * T_, HID_, IN_);

  // PLAIN launch (no cooperative API): 256 blocks, 256 threads, 35 KB LDS.
  rnn_scan4<<<dim3(256), dim3(256), 0, stream>>>(Wt, hall, cnt);

  gemm_bias<<<dim3(OUT_ / 128, (B_ * T_) / 128), 256, 0, stream>>>(
      hall, W_out, b_out, out, B_ * T_, OUT_, HID_);
}

// Round 5
// 6435.698 us; speedup vs baseline: 3.3115x; 1.5110x over previous
//
#include <hip/hip_runtime.h>

#define B_   64
#define T_   512
#define IN_  512
#define HID_ 1024
#define OUT_ 512

#define BROW 1092        // hs staging row stride (floats): 1024 data + skew pads
#define RED_STRIDE 260   // reduction slice stride (floats), aliases hs
#define HS_FLOATS 8728   // 34.9 KB static LDS

// ---------------------------------------------------------------------------
// K0: transpose W_hh [j][k] -> Wt [k][j] so scan W reads are lane-coalesced.
// ---------------------------------------------------------------------------
__global__ __launch_bounds__(256) void transpose_whh(const float* __restrict__ W,
                                                     float* __restrict__ Wt) {
  __shared__ float tile[32][33];
  const int bx = blockIdx.x * 32;  // k
  const int by = blockIdx.y * 32;  // j
  const int tx = threadIdx.x;
  const int ty = threadIdx.y;
#pragma unroll
  for (int i = 0; i < 32; i += 8)
    tile[ty + i][tx] = W[(size_t)(by + ty + i) * HID_ + bx + tx];
  __syncthreads();
#pragma unroll
  for (int i = 0; i < 32; i += 8)
    Wt[(size_t)(bx + ty + i) * HID_ + by + tx] = tile[tx][ty + i];
}

// ---------------------------------------------------------------------------
// K1/K3: C[M,N] = A[M,K] @ B[N,K]^T + bias[N].  fp32, 128x128 tile, BK=8.
// ---------------------------------------------------------------------------
__global__ __launch_bounds__(256) void gemm_bias(const float* __restrict__ A,
                                                 const float* __restrict__ Bm,
                                                 const float* __restrict__ bias,
                                                 float* __restrict__ C,
                                                 int M, int N, int K) {
  __shared__ float As[8][128];
  __shared__ float Bs[8][128];
  const int bm = blockIdx.y * 128;
  const int bn = blockIdx.x * 128;
  const int tid = threadIdx.x;
  const int tr = (tid / 16) * 8;
  const int tc = (tid % 16) * 8;
  const int lr = tid / 2;
  const int lk = (tid % 2) * 4;

  float acc[8][8];
#pragma unroll
  for (int i = 0; i < 8; i++)
#pragma unroll
    for (int j = 0; j < 8; j++) acc[i][j] = 0.f;

  for (int k0 = 0; k0 < K; k0 += 8) {
    float4 a = *(const float4*)&A[(size_t)(bm + lr) * K + k0 + lk];
    float4 b = *(const float4*)&Bm[(size_t)(bn + lr) * K + k0 + lk];
    As[lk + 0][lr] = a.x; As[lk + 1][lr] = a.y;
    As[lk + 2][lr] = a.z; As[lk + 3][lr] = a.w;
    Bs[lk + 0][lr] = b.x; Bs[lk + 1][lr] = b.y;
    Bs[lk + 2][lr] = b.z; Bs[lk + 3][lr] = b.w;
    __syncthreads();
#pragma unroll
    for (int k = 0; k < 8; k++) {
      float av[8], bv[8];
#pragma unroll
      for (int i = 0; i < 8; i++) av[i] = As[k][tr + i];
#pragma unroll
      for (int j = 0; j < 8; j++) bv[j] = Bs[k][tc + j];
#pragma unroll
      for (int i = 0; i < 8; i++)
#pragma unroll
        for (int j = 0; j < 8; j++) acc[i][j] += av[i] * bv[j];
    }
    __syncthreads();
  }

#pragma unroll
  for (int i = 0; i < 8; i++) {
#pragma unroll
    for (int j = 0; j < 8; j += 4) {
      float4 o;
      o.x = acc[i][j + 0] + bias[bn + tc + j + 0];
      o.y = acc[i][j + 1] + bias[bn + tc + j + 1];
      o.z = acc[i][j + 2] + bias[bn + tc + j + 2];
      o.w = acc[i][j + 3] + bias[bn + tc + j + 3];
      *(float4*)&C[(size_t)(bm + tr + i) * N + bn + tc + j] = o;
    }
  }
}

// ---------------------------------------------------------------------------
// K2: persistent scan, plain launch. 256 blocks = 32 j-slices x 8 groups.
// NO fences, NO fetch_add: flag-per-block barrier through L3.  All cross-
// block data moves via agent-scope (sc0 sc1) atomics = L3 coherence point;
// __syncthreads' vmcnt(0) drain before the flag store gives "flag visible
// => h visible".  W stays L2-resident (never invalidated).
// Thread map: q=tid&7 -> 4-j quad, ks=tid>>3 (0..31) -> 32-k slice.
// Per thread: 32k x 4j x 8b = 1024 FMA; W reads dedup'd (128 KB/block/step).
// ---------------------------------------------------------------------------
__global__ __launch_bounds__(256) void rnn_scan5(const float* __restrict__ Wt,
                                                 float* __restrict__ hall,
                                                 int* __restrict__ flags) {
  __shared__ float hs[HS_FLOATS];  // staging [8][BROW]; red alias [32][RED_STRIDE]

  const int bid = blockIdx.x;
  const int jg = bid & 31;
  const int bg = bid >> 5;
  const int j0 = jg * 32;
  const int b0 = bg * 8;
  const int tid = threadIdx.x;
  const int q  = tid & 7;
  const int ks = tid >> 3;

  const float* wbase = Wt + (size_t)(ks * 32) * HID_ + j0 + q * 4;
  const float* hsbase = hs + ks * 32 + (ks >> 1) * 4;

  for (int t = 0; t < T_; ++t) {
    // --- wait for step t-1 (parallel flag poll, wave 0 only)
    if (t > 0 && tid < 64) {
      const int* f = flags + (((bg << 9) + (t - 1)) << 5) + (tid & 31);
      while (true) {
        int v = __hip_atomic_load(f, __ATOMIC_RELAXED, __HIP_MEMORY_SCOPE_AGENT);
        if (__ballot(v != 0) == ~0ull) break;
      }
      __asm__ __volatile__("" ::: "memory");
    }
    __syncthreads();

    // --- prefetch xp (own j-slice of row t; block-private)
    float4 xpv = make_float4(0.f, 0.f, 0.f, 0.f);
    float* xpaddr = nullptr;
    if (tid < 64) {
      xpaddr = &hall[((size_t)(b0 + (tid >> 3)) * T_ + t) * HID_ + j0 + (tid & 7) * 4];
      xpv = *(const float4*)xpaddr;
    }

    float4 acc[8];
#pragma unroll
    for (int bi = 0; bi < 8; ++bi) acc[bi] = make_float4(0.f, 0.f, 0.f, 0.f);

    if (t > 0) {
      const int tp = t - 1;
      // --- stage h(t-1): 8 rows x 1024 floats via coherent u64 loads
#pragma unroll
      for (int s = 0; s < 16; ++s) {
        const int F2 = tid + 256 * s;
        const int b  = F2 >> 9;
        const int k2 = F2 & 511;
        const unsigned long long* src = (const unsigned long long*)
            &hall[((size_t)(b0 + b) * T_ + tp) * HID_ + 2 * k2];
        unsigned long long v =
            __hip_atomic_load(src, __ATOMIC_RELAXED, __HIP_MEMORY_SCOPE_AGENT);
        *(unsigned long long*)&hs[b * BROW + 2 * k2 + (k2 >> 5) * 4] = v;
      }
      __syncthreads();

      // --- compute: 8 groups of 4 k; per g: 4k x 4j x 8b = 128 FMA
#pragma unroll
      for (int g = 0; g < 8; ++g) {
        const int kk = g * 4;
        const float* wp = wbase + (size_t)kk * HID_;
        const float4 w0 = *(const float4*)(wp);
        const float4 w1 = *(const float4*)(wp + HID_);
        const float4 w2 = *(const float4*)(wp + 2 * HID_);
        const float4 w3 = *(const float4*)(wp + 3 * HID_);
#pragma unroll
        for (int bi = 0; bi < 8; ++bi) {
          const float4 hv = *(const float4*)(hsbase + bi * BROW + kk);
          acc[bi].x += hv.x * w0.x + hv.y * w1.x + hv.z * w2.x + hv.w * w3.x;
          acc[bi].y += hv.x * w0.y + hv.y * w1.y + hv.z * w2.y + hv.w * w3.y;
          acc[bi].z += hv.x * w0.z + hv.y * w1.z + hv.z * w2.z + hv.w * w3.z;
          acc[bi].w += hv.x * w0.w + hv.y * w1.w + hv.z * w2.w + hv.w * w3.w;
        }
      }
      __syncthreads();  // all hs reads done before red overwrites
    }

    // --- write partial sums to red (aliases hs)
#pragma unroll
    for (int bi = 0; bi < 8; ++bi)
      *(float4*)&hs[ks * RED_STRIDE + bi * 32 + q * 4] = acc[bi];
    __syncthreads();

    // --- reduce 32 k-slices, tanh, publish h(t) to the coherence point
    if (tid < 64) {
      const int off = (tid >> 3) * 32 + (tid & 7) * 4;
      float4 sum = make_float4(0.f, 0.f, 0.f, 0.f);
#pragma unroll
      for (int kss = 0; kss < 32; ++kss) {
        const float4 r = *(const float4*)&hs[kss * RED_STRIDE + off];
        sum.x += r.x; sum.y += r.y; sum.z += r.z; sum.w += r.w;
      }
      union { float f[4]; unsigned long long u[2]; } pk;
      pk.f[0] = tanhf(sum.x + xpv.x);
      pk.f[1] = tanhf(sum.y + xpv.y);
      pk.f[2] = tanhf(sum.z + xpv.z);
      pk.f[3] = tanhf(sum.w + xpv.w);
      unsigned long long* dst = (unsigned long long*)xpaddr;
      __hip_atomic_store(dst + 0, pk.u[0], __ATOMIC_RELAXED, __HIP_MEMORY_SCOPE_AGENT);
      __hip_atomic_store(dst + 1, pk.u[1], __ATOMIC_RELAXED, __HIP_MEMORY_SCOPE_AGENT);
    }
    __syncthreads();  // vmcnt(0): h stores acked at L3 before flag store

    // --- arrival: one agent store to this block's own flag slot
    if (tid == 0)
      __hip_atomic_store(flags + (((bg << 9) + t) << 5) + jg, 1,
                         __ATOMIC_RELAXED, __HIP_MEMORY_SCOPE_AGENT);
  }
}

// ---------------------------------------------------------------------------
extern "C" void kernel_launch(void* const* d_in, const int* in_sizes, int n_in,
                              void* d_out, int out_size, void* d_ws, size_t ws_size,
                              hipStream_t stream) {
  (void)in_sizes; (void)n_in; (void)out_size; (void)ws_size;
  const float* input = (const float*)d_in[0];
  const float* W_ih  = (const float*)d_in[1];
  const float* W_hh  = (const float*)d_in[2];
  const float* bias  = (const float*)d_in[3];
  const float* W_out = (const float*)d_in[4];
  const float* b_out = (const float*)d_in[5];
  float* out = (float*)d_out;

  float* Wt   = (float*)d_ws;                  // 4 MiB
  float* hall = Wt + (size_t)HID_ * HID_;      // 128 MiB (x_proj, then h)
  // Flags live in the head of d_out: zeroed here, overwritten by K3 at the end.
  int* flags = (int*)d_out;                    // 8 groups x 512 t x 32 slots = 512 KiB

  hipMemsetAsync(flags, 0, (size_t)8 * T_ * 32 * sizeof(int), stream);

  transpose_whh<<<dim3(32, 32), dim3(32, 8), 0, stream>>>(W_hh, Wt);

  gemm_bias<<<dim3(HID_ / 128, (B_ * T_) / 128), 256, 0, stream>>>(
      input, W_ih, bias, hall, B_ * T_, HID_, IN_);

  rnn_scan5<<<dim3(256), dim3(256), 0, stream>>>(Wt, hall, flags);

  gemm_bias<<<dim3(OUT_ / 128, (B_ * T_) / 128), 256, 0, stream>>>(
      hall, W_out, b_out, out, B_ * T_, OUT_, HID_);
}